// Round 6
// baseline (384.798 us; speedup 1.0000x reference)
//
#include <hip/hip_runtime.h>
#include <hip/hip_bf16.h>
#include <stdint.h>

#define BB 4
#define SS 2048
#define DD 1024
#define HH 16
#define DKK 64
#define MT (BB*SS)   // 8192
#define KK DD        // 1024

typedef __attribute__((ext_vector_type(8))) short bf16x8;
typedef __attribute__((ext_vector_type(4))) float f32x4;
typedef __attribute__((ext_vector_type(8))) unsigned short u16x8;

__device__ __forceinline__ unsigned short f2bf(float f){
  union { float f; unsigned u; } x; x.f = f;
  unsigned r = x.u + 0x7fffu + ((x.u >> 16) & 1u);   // RNE
  return (unsigned short)(r >> 16);
}

// fast float->bf16 (compiler lowers pairs to v_cvt_pk_bf16_f32; m240)
__device__ __forceinline__ short bfc(float x){
  return (short)__builtin_bit_cast(unsigned short, (__bf16)x);
}

// guaranteed single-instruction 2^x (v_exp_f32 IS exp2; gfx9 VALU deps HW-interlocked)
__device__ __forceinline__ float ex2(float x){
#if __has_builtin(__builtin_amdgcn_exp2f)
  return __builtin_amdgcn_exp2f(x);
#else
  float r;
  asm("v_exp_f32 %0, %1" : "=v"(r) : "v"(x));
  return r;
#endif
}

__device__ __forceinline__ float fm3(float a, float b, float c){
  return fmaxf(fmaxf(a, b), c);    // clang fuses to v_max3_f32
}

__device__ __forceinline__ void gll16(const void* g, void* l){
  __builtin_amdgcn_global_load_lds(
      (const __attribute__((address_space(1))) void*)g,
      (__attribute__((address_space(3))) void*)l, 16, 0, 0);
}

// ---------------- fp32 -> bf16 convert (8 elems/thread), 3 tensors ----------------
__global__ __launch_bounds__(256) void cvt_bf16_3(const float* __restrict__ q,
                                                  const float* __restrict__ k,
                                                  const float* __restrict__ v,
                                                  unsigned short* __restrict__ qo,
                                                  unsigned short* __restrict__ ko,
                                                  unsigned short* __restrict__ vo){
  const float* in = blockIdx.y==0 ? q : blockIdx.y==1 ? k : v;
  unsigned short* out = blockIdx.y==0 ? qo : blockIdx.y==1 ? ko : vo;
  int i = blockIdx.x * 256 + threadIdx.x;
  const f32x4* p = (const f32x4*)in;
  f32x4 a = p[2*i], b = p[2*i+1];
  u16x8 o;
  #pragma unroll
  for (int j=0;j<4;j++){ o[j] = f2bf(a[j]); o[4+j] = f2bf(b[j]); }
  ((u16x8*)out)[i] = o;
}

// ---------------- weights: transpose to [N][K] bf16, fuse fc_w*Wq ----------------
__global__ __launch_bounds__(256) void prep_weights(
    const float* __restrict__ fc, const float* __restrict__ Wq,
    const float* __restrict__ Wk, const float* __restrict__ Wv,
    const float* __restrict__ Wo,
    unsigned short* __restrict__ Wqt, unsigned short* __restrict__ Wkt,
    unsigned short* __restrict__ Wvt, unsigned short* __restrict__ Wot){
  __shared__ float tile[32][33];
  int which = blockIdx.y;
  const float* src = which==0?Wq: which==1?Wk: which==2?Wv:Wo;
  unsigned short* dst = which==0?Wqt: which==1?Wkt: which==2?Wvt:Wot;
  int k0 = (blockIdx.x & 31)*32, n0 = (blockIdx.x >> 5)*32;
  int tid = threadIdx.x;
  #pragma unroll
  for (int i=0;i<4;i++){
    int e = tid + i*256; int r = e>>5, c = e&31;
    float v = src[(size_t)(k0+r)*DD + n0 + c];
    if (which==0) v *= fc[(size_t)(k0+r)*DD + n0 + c];
    tile[r][c] = v;
  }
  __syncthreads();
  #pragma unroll
  for (int i=0;i<4;i++){
    int e = tid + i*256; int r = e>>5, c = e&31;
    dst[(size_t)(n0+r)*DD + k0 + c] = f2bf(tile[c][r]);
  }
}

// ================= GEMM body (m97 structure, 128x128 tile, BK=32) ==============
// EPI=0: bf16*(scale) in [B,H,S,DK] head layout.  EPI=1: fp32 [M][N].
#define GEMM_BODY(EPI, A, Bt, bias, scale, Cout, m0, n0)                          \
  {                                                                               \
  const int tid = threadIdx.x;                                                    \
  const int lane = tid & 63, wid = tid >> 6;                                      \
  const int wm = wid >> 1, wn = wid & 1;                                          \
  const int g = lane >> 4, lr = lane & 15;                                        \
  f32x4 acc[4][4];                                                                \
  _Pragma("unroll")                                                               \
  for (int i=0;i<4;i++)                                                           \
    _Pragma("unroll")                                                             \
    for (int j=0;j<4;j++) acc[i][j] = (f32x4){0.f,0.f,0.f,0.f};                   \
  const char* gaBase = (const char*)((A)  + (size_t)(m0) * KK);                   \
  const char* gbBase = (const char*)((Bt) + (size_t)(n0) * KK);                   \
  auto stage = [&](int buf, int kt){                                              \
    _Pragma("unroll")                                                             \
    for (int is=0; is<2; ++is){                                                   \
      int t = is*4096 + wid*1024 + lane*16;                                       \
      int row = t >> 6, col = t & 63;                                             \
      gll16(gaBase + (size_t)row*(KK*2) + (size_t)kt*64 + col,                    \
            (char*)&Asb[buf][0] + is*4096 + wid*1024);                            \
      gll16(gbBase + (size_t)row*(KK*2) + (size_t)kt*64 + col,                    \
            (char*)&Bsb[buf][0] + is*4096 + wid*1024);                            \
    }                                                                             \
  };                                                                              \
  stage(0, 0);                                                                    \
  __syncthreads();                                                                \
  int cur = 0;                                                                    \
  for (int kt = 0; kt < KK/32; ++kt){                                             \
    if (kt + 1 < KK/32) stage(cur^1, kt+1);                                       \
    bf16x8 af[4], bfr[4];                                                         \
    _Pragma("unroll")                                                             \
    for (int f=0; f<4; ++f){                                                      \
      int ar = wm*64 + f*16 + lr;                                                 \
      af[f]  = *(const bf16x8*)&Asb[cur][ar*32 + g*8];                            \
      int br = wn*64 + f*16 + lr;                                                 \
      bfr[f] = *(const bf16x8*)&Bsb[cur][br*32 + g*8];                            \
    }                                                                             \
    _Pragma("unroll")                                                             \
    for (int i=0;i<4;i++)                                                         \
      _Pragma("unroll")                                                           \
      for (int j=0;j<4;j++)                                                       \
        acc[i][j] = __builtin_amdgcn_mfma_f32_16x16x32_bf16(af[i], bfr[j], acc[i][j], 0, 0, 0); \
    __syncthreads();                                                              \
    cur ^= 1;                                                                     \
  }                                                                               \
  _Pragma("unroll")                                                               \
  for (int j=0;j<4;j++){                                                          \
    int n = (n0) + wn*64 + j*16 + lr;                                             \
    float bv = (bias)[n];                                                         \
    _Pragma("unroll")                                                             \
    for (int i=0;i<4;i++){                                                        \
      int mbase = (m0) + wm*64 + i*16 + g*4;                                      \
      _Pragma("unroll")                                                           \
      for (int r=0;r<4;r++){                                                      \
        int m = mbase + r;                                                        \
        float v = (acc[i][j][r] + bv) * (scale);                                  \
        if (EPI == 0){                                                            \
          int b = m >> 11, s = m & (SS-1);                                        \
          int h = n >> 6, dk = n & 63;                                            \
          ((unsigned short*)(Cout))[(((size_t)(b*HH + h))*SS + s)*DKK + dk] = f2bf(v); \
        } else {                                                                  \
          ((float*)(Cout))[(size_t)m*DD + n] = v;                                 \
        }                                                                         \
      }                                                                           \
    }                                                                             \
  }                                                                               \
  }

// Merged Q/K/V projection GEMM: 1536 blocks (3 x 512), XCD-chunked per matrix.
__global__ __launch_bounds__(256) void gemm_qkv(
    const unsigned short* __restrict__ Aq, const unsigned short* __restrict__ Ak,
    const unsigned short* __restrict__ Av,
    const unsigned short* __restrict__ Wq, const unsigned short* __restrict__ Wk,
    const unsigned short* __restrict__ Wv,
    const float* __restrict__ bq, const float* __restrict__ bk,
    const float* __restrict__ bv, float qscale,
    unsigned short* __restrict__ Qo, unsigned short* __restrict__ Ko,
    unsigned short* __restrict__ Vo){
  __shared__ __align__(16) unsigned short Asb[2][128*32];
  __shared__ __align__(16) unsigned short Bsb[2][128*32];
  const int u = blockIdx.x;
  const int which = u % 3, v = u / 3;
  const int xcd = v & 7, jj = v >> 3;
  const int by = xcd*8 + (jj>>3), bx = jj & 7;
  const int m0 = by * 128, n0 = bx * 128;
  const unsigned short* A  = which==0 ? Aq : which==1 ? Ak : Av;
  const unsigned short* Bt = which==0 ? Wq : which==1 ? Wk : Wv;
  const float* bias        = which==0 ? bq : which==1 ? bk : bv;
  unsigned short* C        = which==0 ? Qo : which==1 ? Ko : Vo;
  float scale = which==0 ? qscale : 1.0f;
  GEMM_BODY(0, A, Bt, bias, scale, C, m0, n0)
}

// Output projection GEMM (fp32 out), 512 blocks.
__global__ __launch_bounds__(256) void gemm_o(
    const unsigned short* __restrict__ A, const unsigned short* __restrict__ Bt,
    const float* __restrict__ bias, float* __restrict__ Cout){
  __shared__ __align__(16) unsigned short Asb[2][128*32];
  __shared__ __align__(16) unsigned short Bsb[2][128*32];
  const int sidx = blockIdx.x;
  const int xcd = sidx & 7, jj = sidx >> 3;
  const int by = xcd*8 + (jj>>3), bx = jj & 7;
  const int m0 = by * 128, n0 = bx * 128;
  GEMM_BODY(1, A, Bt, bias, 1.0f, Cout, m0, n0)
}

// ---------------- V [BH][S][64] -> Vt [BH][64][sigma(S)] ----------------
// sigma permutes s within each 64-tile (bit perm: out = b5,b3,b2,b4,b1,b0) so the
// attn PV B-fragment (8 k-slots of one lane group) is 16B-contiguous.
__global__ __launch_bounds__(256) void transpose_v(const unsigned short* __restrict__ V,
                                                   unsigned short* __restrict__ Vt){
  __shared__ unsigned short t[64][72];
  int bh = blockIdx.y; int s0 = blockIdx.x*64;
  const unsigned short* src = V + ((size_t)bh*SS + s0)*DKK;
  int tid = threadIdx.x;
  #pragma unroll
  for (int i=0;i<2;i++){
    int e = (tid + i*256)*8; int r = e>>6, c = e&63;
    int rp = (r & 35) | ((r & 12) << 1) | ((r & 16) >> 2);   // sigma(r)
    u16x8 v = *(const u16x8*)(src + (size_t)r*DKK + c);
    #pragma unroll
    for (int j=0;j<8;j++) t[c+j][rp] = v[j];
  }
  __syncthreads();
  unsigned short* dst = Vt + ((size_t)bh*DKK)*SS + s0;
  #pragma unroll
  for (int i=0;i<2;i++){
    int e = (tid + i*256)*8; int d = e>>6, c = e&63;
    u16x8 v = *(const u16x8*)(&t[d][c]);
    *(u16x8*)(dst + (size_t)d*SS + c) = v;
  }
}

// ---------------- flash attention (128 q/block, 32 q/wave) ----------------
// T4 counted-vmcnt pipeline: raw s_barrier (no vmcnt drain) + derived waits.
//   iter t: s_barrier                  // all waves done reading slot (t-1)&1
//           stage(t+1) -> slot (t+1)&1 // 4 gll16/wave; overwrites (t-1)'s slot
//           s_waitcnt vmcnt(4)         // tile t (older 4 loads) complete
//           s_barrier                  // every wave confirmed its share of tile t
//           body(t)                    // prefetch of t+1 stays in flight
// Last iter peels to vmcnt(0). XCD swizzle: all 16 q-blocks of a (b,h) on one
// XCD -> K/V (512KB) L2-resident.
__global__ __launch_bounds__(256) void attn(
    const unsigned short* __restrict__ Qg,
    const unsigned short* __restrict__ Kg,
    const unsigned short* __restrict__ Vtg,
    unsigned short* __restrict__ Xg){
  __shared__ __align__(16) unsigned short Ks[2][64*64];
  __shared__ __align__(16) unsigned short Vs[2][64*64];
  const int tid = threadIdx.x;
  const int lane = tid & 63, wid = tid >> 6;
  const int g = lane >> 4, lr = lane & 15;
  const int u0 = blockIdx.x;
  const int wk = (u0 & 7) * 128 + (u0 >> 3);   // bijective XCD chunking (1024 = 8*128)
  const int bh = wk >> 4;
  const int q0 = (wk & 15) * 128;

  const unsigned short* Qrow = Qg + ((size_t)bh*SS + q0)*DKK;
  const char* Kbase = (const char*)(Kg + (size_t)bh*SS*DKK);
  const char* Vbase = (const char*)(Vtg + (size_t)bh*DKK*SS);

  auto stageK = [&](int buf, int it){
    const char* gk = Kbase + (size_t)it*8192;
    #pragma unroll
    for (int is=0; is<2; ++is){
      int t = is*4096 + wid*1024 + lane*16;
      int row = t >> 7;
      int col = (t & 127) ^ ((row & 7) << 4);
      gll16(gk + row*128 + col, (char*)&Ks[buf][0] + is*4096 + wid*1024);
    }
  };
  auto stageV = [&](int buf, int it){
    #pragma unroll
    for (int is=0; is<2; ++is){
      int t = is*4096 + wid*1024 + lane*16;
      int row = t >> 7;
      int col = (t & 127) ^ ((row & 7) << 4);
      gll16(Vbase + (size_t)row*(SS*2) + (size_t)it*128 + col,
            (char*)&Vs[buf][0] + is*4096 + wid*1024);
    }
  };

  // Q fragments direct from global, FIRST (oldest in vmcnt queue)
  bf16x8 qf[2][2];
  #pragma unroll
  for (int u=0; u<2; ++u){
    int qrow = wid*32 + u*16 + lr;
    #pragma unroll
    for (int h2=0; h2<2; ++h2)
      qf[u][h2] = *(const bf16x8*)(Qrow + (size_t)qrow*DKK + g*8 + h2*32);
  }
  stageK(0, 0); stageV(0, 0);

  f32x4 Xf[2][4];
  #pragma unroll
  for (int u=0; u<2; ++u)
    #pragma unroll
    for (int d=0; d<4; ++d) Xf[u][d] = (f32x4){0.f,0.f,0.f,0.f};
  const f32x4 Zv = (f32x4){0.f,0.f,0.f,0.f};
  float m2[2] = {-1e30f, -1e30f}, ell[2] = {0.f, 0.f};
  const int sw2 = (lr & 7) << 4;

  auto body = [&](int cbuf){
    const char* Kb = (const char*)&Ks[cbuf][0];
    const char* Vb = (const char*)&Vs[cbuf][0];
    // ---- S^T = K @ Q^T : lane holds S[kv = s4*16 + g*4 + r][q = u*16 + lr] ----
    f32x4 st[4][2];
    __builtin_amdgcn_s_setprio(1);
    #pragma unroll
    for (int s4=0; s4<4; ++s4){
      int rb = (s4*16 + lr) * 128;
      bf16x8 k0 = *(const bf16x8*)(Kb + rb + ((g*16     ) ^ sw2));
      bf16x8 k1 = *(const bf16x8*)(Kb + rb + ((g*16 + 64) ^ sw2));
      st[s4][0] = __builtin_amdgcn_mfma_f32_16x16x32_bf16(k0, qf[0][0], Zv,        0,0,0);
      st[s4][0] = __builtin_amdgcn_mfma_f32_16x16x32_bf16(k1, qf[0][1], st[s4][0], 0,0,0);
      st[s4][1] = __builtin_amdgcn_mfma_f32_16x16x32_bf16(k0, qf[1][0], Zv,        0,0,0);
      st[s4][1] = __builtin_amdgcn_mfma_f32_16x16x32_bf16(k1, qf[1][1], st[s4][1], 0,0,0);
    }
    __builtin_amdgcn_s_setprio(0);

    bf16x8 pa[2][2];
    #pragma unroll
    for (int u=0; u<2; ++u){
      // online softmax, log2 domain, defer-max THR=8
      float t0 = fm3(st[0][u][0], st[0][u][1], st[0][u][2]);
      float t1 = fm3(st[0][u][3], st[1][u][0], st[1][u][1]);
      float t2 = fm3(st[1][u][2], st[1][u][3], st[2][u][0]);
      float t3 = fm3(st[2][u][1], st[2][u][2], st[2][u][3]);
      float t4 = fm3(st[3][u][0], st[3][u][1], st[3][u][2]);
      float tmax = fm3(fm3(t0, t1, t2), fmaxf(t3, t4), st[3][u][3]);
      tmax = fmaxf(tmax, __shfl_xor(tmax, 16));
      tmax = fmaxf(tmax, __shfl_xor(tmax, 32));
      if (__any(tmax > m2[u] + 8.f)){
        float mn = fmaxf(m2[u], tmax);
        float sc = ex2(m2[u] - mn);
        m2[u] = mn;
        ell[u] *= sc;
        #pragma unroll
        for (int r=0; r<4; ++r){
          float scr = __shfl(sc, g*4 + r);
          #pragma unroll
          for (int d=0; d<4; ++d) Xf[u][d][r] *= scr;
        }
      }
      #pragma unroll
      for (int s4=0; s4<4; ++s4)
        #pragma unroll
        for (int r=0; r<4; ++r) st[s4][u][r] = ex2(st[s4][u][r] - m2[u]);
      float ps0 = (st[0][u][0]+st[0][u][1]) + (st[0][u][2]+st[0][u][3]);
      float ps1 = (st[1][u][0]+st[1][u][1]) + (st[1][u][2]+st[1][u][3]);
      float ps2 = (st[2][u][0]+st[2][u][1]) + (st[2][u][2]+st[2][u][3]);
      float ps3 = (st[3][u][0]+st[3][u][1]) + (st[3][u][2]+st[3][u][3]);
      ell[u] += (ps0+ps1) + (ps2+ps3);
      // P -> bf16 A-fragments (k-slot map pi(g,j,mh) = 32mh+16(j>>2)+4g+(j&3))
      #pragma unroll
      for (int j=0; j<8; ++j){
        pa[u][0][j] = bfc(st[(j>>2)    ][u][j&3]);
        pa[u][1][j] = bfc(st[2 + (j>>2)][u][j&3]);
      }
    }

    // ---- X += P @ V  (sigma-permuted Vt; b0/b1 shared by both q-subtiles) ----
    __builtin_amdgcn_s_setprio(1);
    #pragma unroll
    for (int d=0; d<4; ++d){
      int rb = (d*16 + lr) * 128;
      bf16x8 b0 = *(const bf16x8*)(Vb + rb + ((g*16     ) ^ sw2));
      bf16x8 b1 = *(const bf16x8*)(Vb + rb + ((g*16 + 64) ^ sw2));
      Xf[0][d] = __builtin_amdgcn_mfma_f32_16x16x32_bf16(pa[0][0], b0, Xf[0][d], 0,0,0);
      Xf[0][d] = __builtin_amdgcn_mfma_f32_16x16x32_bf16(pa[0][1], b1, Xf[0][d], 0,0,0);
      Xf[1][d] = __builtin_amdgcn_mfma_f32_16x16x32_bf16(pa[1][0], b0, Xf[1][d], 0,0,0);
      Xf[1][d] = __builtin_amdgcn_mfma_f32_16x16x32_bf16(pa[1][1], b1, Xf[1][d], 0,0,0);
    }
    __builtin_amdgcn_s_setprio(0);
  };

  for (int it = 0; it < SS/64; it += 2){
    // ---- t = it (even), consume slot 0 ----
    __builtin_amdgcn_s_barrier();                       // all waves done reading slot 1
    stageK(1, it+1); stageV(1, it+1);                   // it+1 <= 31 always
    asm volatile("s_waitcnt vmcnt(4)" ::: "memory");    // tile it fully loaded (ours)
    __builtin_amdgcn_s_barrier();                       // everyone's share loaded
    __builtin_amdgcn_sched_barrier(0);
    body(0);
    // ---- t = it+1 (odd), consume slot 1 ----
    __builtin_amdgcn_s_barrier();
    if (it + 2 < SS/64){
      stageK(0, it+2); stageV(0, it+2);
      asm volatile("s_waitcnt vmcnt(4)" ::: "memory");
    } else {
      asm volatile("s_waitcnt vmcnt(0)" ::: "memory");  // final tile: full drain
    }
    __builtin_amdgcn_s_barrier();
    __builtin_amdgcn_sched_barrier(0);
    body(1);
  }

  // ---- finalize: reduce partial ell over lane-groups, divide, store ----
  int b = bh >> 4, h = bh & 15;
  #pragma unroll
  for (int u=0; u<2; ++u){
    float elt = ell[u];
    elt += __shfl_xor(elt, 16);
    elt += __shfl_xor(elt, 32);
    float rinv[4];
    #pragma unroll
    for (int r=0; r<4; ++r) rinv[r] = 1.0f / __shfl(elt, g*4 + r);
    #pragma unroll
    for (int d=0; d<4; ++d)
      #pragma unroll
      for (int r=0; r<4; ++r){
        int s = q0 + wid*32 + u*16 + g*4 + r;
        int col = h*64 + d*16 + lr;
        Xg[((size_t)b*SS + s)*DD + col] = f2bf(Xf[u][d][r] * rinv[r]);
      }
  }
}

// ---------------- host ----------------
extern "C" void kernel_launch(void* const* d_in, const int* in_sizes, int n_in,
                              void* d_out, int out_size, void* d_ws, size_t ws_size,
                              hipStream_t stream){
  (void)in_sizes; (void)n_in; (void)out_size; (void)ws_size;
  const float* query = (const float*)d_in[0];
  const float* key   = (const float*)d_in[1];
  const float* value = (const float*)d_in[2];
  const float* fc_w  = (const float*)d_in[3];
  const float* Wq    = (const float*)d_in[4];
  const float* bq    = (const float*)d_in[5];
  const float* Wk    = (const float*)d_in[6];
  const float* bk    = (const float*)d_in[7];
  const float* Wv    = (const float*)d_in[8];
  const float* bv    = (const float*)d_in[9];
  const float* Wo    = (const float*)d_in[10];
  const float* bo    = (const float*)d_in[11];

  char* ws = (char*)d_ws;
  const size_t EL = (size_t)BB*SS*DD;          // 8388608 elems
  size_t off = 0;
  auto alloc = [&](size_t bytes){ size_t o = off; off += (bytes + 255) & ~(size_t)255; return o; };
  unsigned short* qb  = (unsigned short*)(ws + alloc(EL*2));
  unsigned short* kb  = (unsigned short*)(ws + alloc(EL*2));
  unsigned short* vb  = (unsigned short*)(ws + alloc(EL*2));
  unsigned short* Wqt = (unsigned short*)(ws + alloc((size_t)DD*DD*2));
  unsigned short* Wkt = (unsigned short*)(ws + alloc((size_t)DD*DD*2));
  unsigned short* Wvt = (unsigned short*)(ws + alloc((size_t)DD*DD*2));
  unsigned short* Wot = (unsigned short*)(ws + alloc((size_t)DD*DD*2));
  unsigned short* Qh  = (unsigned short*)(ws + alloc(EL*2));
  unsigned short* Kh  = (unsigned short*)(ws + alloc(EL*2));
  unsigned short* Vh  = (unsigned short*)(ws + alloc(EL*2));
  // Aliased buffers:
  //   Vth aliases vb (vb dead after V-projection GEMM; transpose runs after it)
  //   Xh  aliases qb (qb dead after Q-projection GEMM; attn runs after it)
  unsigned short* Vth = vb;
  unsigned short* Xh  = qb;

  const float SC2 = 0.18033688011112042f;      // (1/sqrt(64)) * log2(e), folded into Q

  const int nbCvt = (int)(EL / 8 / 256);       // 4096
  cvt_bf16_3<<<dim3(nbCvt, 3), 256, 0, stream>>>(query, key, value, qb, kb, vb);
  prep_weights<<<dim3(1024, 4), 256, 0, stream>>>(fc_w, Wq, Wk, Wv, Wo, Wqt, Wkt, Wvt, Wot);

  gemm_qkv<<<1536, 256, 0, stream>>>(qb, kb, vb, Wqt, Wkt, Wvt, bq, bk, bv, SC2,
                                     Qh, Kh, Vh);

  transpose_v<<<dim3(SS/64, BB*HH), 256, 0, stream>>>(Vh, Vth);
  attn<<<dim3(SS/128 * BB*HH), 256, 0, stream>>>(Qh, Kh, Vth, Xh);

  gemm_o<<<512, 256, 0, stream>>>(Xh, Wot, bo, (float*)d_out);
}

// Round 9
// 380.111 us; speedup vs baseline: 1.0123x; 1.0123x over previous
//
#include <hip/hip_runtime.h>
#include <hip/hip_bf16.h>
#include <stdint.h>

#define BB 4
#define SS 2048
#define DD 1024
#define HH 16
#define DKK 64
#define MT (BB*SS)   // 8192
#define KK DD        // 1024

typedef __attribute__((ext_vector_type(8))) short bf16x8;
typedef __attribute__((ext_vector_type(4))) float f32x4;
typedef __attribute__((ext_vector_type(8))) unsigned short u16x8;
typedef __attribute__((ext_vector_type(4))) unsigned int u32x4;

__device__ __forceinline__ unsigned short f2bf(float f){
  union { float f; unsigned u; } x; x.f = f;
  unsigned r = x.u + 0x7fffu + ((x.u >> 16) & 1u);   // RNE
  return (unsigned short)(r >> 16);
}

// packed f32x2 -> bf16x2 (single v_cvt_pk_bf16_f32; no builtin on gfx950)
__device__ __forceinline__ unsigned cvtpk(float lo, float hi){
  unsigned r;
  asm("v_cvt_pk_bf16_f32 %0, %1, %2" : "=v"(r) : "v"(lo), "v"(hi));
  return r;
}

// guaranteed single-instruction 2^x
__device__ __forceinline__ float ex2(float x){
#if __has_builtin(__builtin_amdgcn_exp2f)
  return __builtin_amdgcn_exp2f(x);
#else
  float r;
  asm("v_exp_f32 %0, %1" : "=v"(r) : "v"(x));
  return r;
#endif
}

__device__ __forceinline__ float fm3(float a, float b, float c){
  return fmaxf(fmaxf(a, b), c);    // clang fuses to v_max3_f32
}

__device__ __forceinline__ void gll16(const void* g, void* l){
  __builtin_amdgcn_global_load_lds(
      (const __attribute__((address_space(1))) void*)g,
      (__attribute__((address_space(3))) void*)l, 16, 0, 0);
}

// ---------------- fp32 -> bf16 convert (8 elems/thread), 3 tensors ----------------
__global__ __launch_bounds__(256) void cvt_bf16_3(const float* __restrict__ q,
                                                  const float* __restrict__ k,
                                                  const float* __restrict__ v,
                                                  unsigned short* __restrict__ qo,
                                                  unsigned short* __restrict__ ko,
                                                  unsigned short* __restrict__ vo){
  const float* in = blockIdx.y==0 ? q : blockIdx.y==1 ? k : v;
  unsigned short* out = blockIdx.y==0 ? qo : blockIdx.y==1 ? ko : vo;
  int i = blockIdx.x * 256 + threadIdx.x;
  const f32x4* p = (const f32x4*)in;
  f32x4 a = p[2*i], b = p[2*i+1];
  u16x8 o;
  #pragma unroll
  for (int j=0;j<4;j++){ o[j] = f2bf(a[j]); o[4+j] = f2bf(b[j]); }
  ((u16x8*)out)[i] = o;
}

// ---------------- weights: transpose to [N][K] bf16, fuse fc_w*Wq ----------------
__global__ __launch_bounds__(256) void prep_weights(
    const float* __restrict__ fc, const float* __restrict__ Wq,
    const float* __restrict__ Wk, const float* __restrict__ Wv,
    const float* __restrict__ Wo,
    unsigned short* __restrict__ Wqt, unsigned short* __restrict__ Wkt,
    unsigned short* __restrict__ Wvt, unsigned short* __restrict__ Wot){
  __shared__ float tile[32][33];
  int which = blockIdx.y;
  const float* src = which==0?Wq: which==1?Wk: which==2?Wv:Wo;
  unsigned short* dst = which==0?Wqt: which==1?Wkt: which==2?Wvt:Wot;
  int k0 = (blockIdx.x & 31)*32, n0 = (blockIdx.x >> 5)*32;
  int tid = threadIdx.x;
  #pragma unroll
  for (int i=0;i<4;i++){
    int e = tid + i*256; int r = e>>5, c = e&31;
    float v = src[(size_t)(k0+r)*DD + n0 + c];
    if (which==0) v *= fc[(size_t)(k0+r)*DD + n0 + c];
    tile[r][c] = v;
  }
  __syncthreads();
  #pragma unroll
  for (int i=0;i<4;i++){
    int e = tid + i*256; int r = e>>5, c = e&31;
    dst[(size_t)(n0+r)*DD + k0 + c] = f2bf(tile[c][r]);
  }
}

// ================= GEMM body (m97 structure, 128x128 tile, BK=32) ==============
// EPI=0: bf16*(scale) in [B,H,S,DK] head layout.  EPI=1: fp32 [M][N].
#define GEMM_BODY(EPI, A, Bt, bias, scale, Cout, m0, n0)                          \
  {                                                                               \
  const int tid = threadIdx.x;                                                    \
  const int lane = tid & 63, wid = tid >> 6;                                      \
  const int wm = wid >> 1, wn = wid & 1;                                          \
  const int g = lane >> 4, lr = lane & 15;                                        \
  f32x4 acc[4][4];                                                                \
  _Pragma("unroll")                                                               \
  for (int i=0;i<4;i++)                                                           \
    _Pragma("unroll")                                                             \
    for (int j=0;j<4;j++) acc[i][j] = (f32x4){0.f,0.f,0.f,0.f};                   \
  const char* gaBase = (const char*)((A)  + (size_t)(m0) * KK);                   \
  const char* gbBase = (const char*)((Bt) + (size_t)(n0) * KK);                   \
  auto stage = [&](int buf, int kt){                                              \
    _Pragma("unroll")                                                             \
    for (int is=0; is<2; ++is){                                                   \
      int t = is*4096 + wid*1024 + lane*16;                                       \
      int row = t >> 6, col = t & 63;                                             \
      gll16(gaBase + (size_t)row*(KK*2) + (size_t)kt*64 + col,                    \
            (char*)&Asb[buf][0] + is*4096 + wid*1024);                            \
      gll16(gbBase + (size_t)row*(KK*2) + (size_t)kt*64 + col,                    \
            (char*)&Bsb[buf][0] + is*4096 + wid*1024);                            \
    }                                                                             \
  };                                                                              \
  stage(0, 0);                                                                    \
  __syncthreads();                                                                \
  int cur = 0;                                                                    \
  for (int kt = 0; kt < KK/32; ++kt){                                             \
    if (kt + 1 < KK/32) stage(cur^1, kt+1);                                       \
    bf16x8 af[4], bfr[4];                                                         \
    _Pragma("unroll")                                                             \
    for (int f=0; f<4; ++f){                                                      \
      int ar = wm*64 + f*16 + lr;                                                 \
      af[f]  = *(const bf16x8*)&Asb[cur][ar*32 + g*8];                            \
      int br = wn*64 + f*16 + lr;                                                 \
      bfr[f] = *(const bf16x8*)&Bsb[cur][br*32 + g*8];                            \
    }                                                                             \
    _Pragma("unroll")                                                             \
    for (int i=0;i<4;i++)                                                         \
      _Pragma("unroll")                                                           \
      for (int j=0;j<4;j++)                                                       \
        acc[i][j] = __builtin_amdgcn_mfma_f32_16x16x32_bf16(af[i], bfr[j], acc[i][j], 0, 0, 0); \
    __syncthreads();                                                              \
    cur ^= 1;                                                                     \
  }                                                                               \
  _Pragma("unroll")                                                               \
  for (int j=0;j<4;j++){                                                          \
    int n = (n0) + wn*64 + j*16 + lr;                                             \
    float bv = (bias)[n];                                                         \
    _Pragma("unroll")                                                             \
    for (int i=0;i<4;i++){                                                        \
      int mbase = (m0) + wm*64 + i*16 + g*4;                                      \
      _Pragma("unroll")                                                           \
      for (int r=0;r<4;r++){                                                      \
        int m = mbase + r;                                                        \
        float v = (acc[i][j][r] + bv) * (scale);                                  \
        if (EPI == 0){                                                            \
          int b = m >> 11, s = m & (SS-1);                                        \
          int h = n >> 6, dk = n & 63;                                            \
          ((unsigned short*)(Cout))[(((size_t)(b*HH + h))*SS + s)*DKK + dk] = f2bf(v); \
        } else {                                                                  \
          ((float*)(Cout))[(size_t)m*DD + n] = v;                                 \
        }                                                                         \
      }                                                                           \
    }                                                                             \
  }                                                                               \
  }

// Merged Q/K/V projection GEMM: 1536 blocks. which = u>>9 so that within each
// 512-block chunk, (u & 7) — the PHYSICAL XCD under round-robin dispatch — matches
// the panel-group swizzle (R7 bug: u%3 scattered panel groups across XCDs).
__global__ __launch_bounds__(256) void gemm_qkv(
    const unsigned short* __restrict__ Aq, const unsigned short* __restrict__ Ak,
    const unsigned short* __restrict__ Av,
    const unsigned short* __restrict__ Wq, const unsigned short* __restrict__ Wk,
    const unsigned short* __restrict__ Wv,
    const float* __restrict__ bq, const float* __restrict__ bk,
    const float* __restrict__ bv, float qscale,
    unsigned short* __restrict__ Qo, unsigned short* __restrict__ Ko,
    unsigned short* __restrict__ Vo){
  __shared__ __align__(16) unsigned short Asb[2][128*32];
  __shared__ __align__(16) unsigned short Bsb[2][128*32];
  const int u = blockIdx.x;
  const int which = u >> 9;
  const int sidx = u & 511;
  const int xcd = sidx & 7, jj = sidx >> 3;
  const int by = xcd*8 + (jj>>3), bx = jj & 7;
  const int m0 = by * 128, n0 = bx * 128;
  const unsigned short* A  = which==0 ? Aq : which==1 ? Ak : Av;
  const unsigned short* Bt = which==0 ? Wq : which==1 ? Wk : Wv;
  const float* bias        = which==0 ? bq : which==1 ? bk : bv;
  unsigned short* C        = which==0 ? Qo : which==1 ? Ko : Vo;
  float scale = which==0 ? qscale : 1.0f;
  GEMM_BODY(0, A, Bt, bias, scale, C, m0, n0)
}

// Output projection GEMM (fp32 out), 512 blocks.
__global__ __launch_bounds__(256) void gemm_o(
    const unsigned short* __restrict__ A, const unsigned short* __restrict__ Bt,
    const float* __restrict__ bias, float* __restrict__ Cout){
  __shared__ __align__(16) unsigned short Asb[2][128*32];
  __shared__ __align__(16) unsigned short Bsb[2][128*32];
  const int sidx = blockIdx.x;
  const int xcd = sidx & 7, jj = sidx >> 3;
  const int by = xcd*8 + (jj>>3), bx = jj & 7;
  const int m0 = by * 128, n0 = bx * 128;
  GEMM_BODY(1, A, Bt, bias, 1.0f, Cout, m0, n0)
}

// ---------------- V [BH][S][64] -> Vt [BH][64][sigma(S)] ----------------
// sigma permutes s within each 64-tile (bit perm: out = b5,b3,b2,b4,b1,b0) so the
// attn PV B-fragment (8 k-slots of one lane group) is 16B-contiguous.
__global__ __launch_bounds__(256) void transpose_v(const unsigned short* __restrict__ V,
                                                   unsigned short* __restrict__ Vt){
  __shared__ unsigned short t[64][72];
  int bh = blockIdx.y; int s0 = blockIdx.x*64;
  const unsigned short* src = V + ((size_t)bh*SS + s0)*DKK;
  int tid = threadIdx.x;
  #pragma unroll
  for (int i=0;i<2;i++){
    int e = (tid + i*256)*8; int r = e>>6, c = e&63;
    int rp = (r & 35) | ((r & 12) << 1) | ((r & 16) >> 2);   // sigma(r)
    u16x8 v = *(const u16x8*)(src + (size_t)r*DKK + c);
    #pragma unroll
    for (int j=0;j<8;j++) t[c+j][rp] = v[j];
  }
  __syncthreads();
  unsigned short* dst = Vt + ((size_t)bh*DKK)*SS + s0;
  #pragma unroll
  for (int i=0;i<2;i++){
    int e = (tid + i*256)*8; int d = e>>6, c = e&63;
    u16x8 v = *(const u16x8*)(&t[d][c]);
    *(u16x8*)(dst + (size_t)d*SS + c) = v;
  }
}

// ---------------- flash attention (64 q/block, 16 q/wave, 5 blocks/CU) ----------------
// Sync: __syncthreads double-buffer (R4-proven deterministic; R6 showed counted-vmcnt
// gains 0). Keeps: tile-rotation desync (rot), V-reg hoist, packed cvt, hoisted
// invariant addresses. R7 race class (raw s_barrier, no compiler fence) eliminated.
__global__ __launch_bounds__(256) void attn(
    const unsigned short* __restrict__ Qg,
    const unsigned short* __restrict__ Kg,
    const unsigned short* __restrict__ Vtg,
    unsigned short* __restrict__ Xg){
  __shared__ __align__(16) unsigned short Ks[2][64*64];
  __shared__ __align__(16) unsigned short Vs[2][64*64];
  const int tid = threadIdx.x;
  const int lane = tid & 63, wid = tid >> 6;
  const int g = lane >> 4, lr = lane & 15;
  const int u0 = blockIdx.x;
  const int wk = (u0 & 7) * 256 + (u0 >> 3);   // bijective XCD chunking (2048 = 8*256)
  const int bh = wk >> 5;
  const int q0 = (wk & 31) * 64;
  const int rot = wk & 31;                      // tile-rotation offset (order-free softmax)

  const unsigned short* Qrow = Qg + ((size_t)bh*SS + q0)*DKK;
  const char* Kbase = (const char*)(Kg + (size_t)bh*SS*DKK);
  const char* Vbase = (const char*)(Vtg + (size_t)bh*DKK*SS);

  // ---- loop-invariant staging offsets (per lane) ----
  const int t0 = wid*1024 + lane*16;            // is=0 LDS byte offset
  const int t1 = 4096 + t0;                     // is=1
  const int r0 = t0 >> 7, r1 = t1 >> 7;
  const int cA0 = (t0 & 127) ^ ((r0 & 7) << 4);
  const int cA1 = (t1 & 127) ^ ((r1 & 7) << 4);
  const int ksrc0 = r0*128 + cA0,      ksrc1 = r1*128 + cA1;       // K tile is contiguous
  const int vsrc0 = r0*(SS*2) + cA0,   vsrc1 = r1*(SS*2) + cA1;    // V rows stride S*2

  auto stageK = [&](int buf, int it){
    const char* gk = Kbase + (size_t)it*8192;
    gll16(gk + ksrc0, (char*)&Ks[buf][0] + t0);
    gll16(gk + ksrc1, (char*)&Ks[buf][0] + t1);
  };
  auto stageV = [&](int buf, int it){
    const char* gv = Vbase + (size_t)it*128;
    gll16(gv + vsrc0, (char*)&Vs[buf][0] + t0);
    gll16(gv + vsrc1, (char*)&Vs[buf][0] + t1);
  };

  // Q fragments direct from global
  bf16x8 qf0, qf1;
  {
    int qrow = wid*16 + lr;
    qf0 = *(const bf16x8*)(Qrow + (size_t)qrow*DKK + g*8);
    qf1 = *(const bf16x8*)(Qrow + (size_t)qrow*DKK + g*8 + 32);
  }
  stageK(0, rot); stageV(0, rot);

  f32x4 Xf[4];
  #pragma unroll
  for (int d=0; d<4; ++d) Xf[d] = (f32x4){0.f,0.f,0.f,0.f};
  const f32x4 Zv = (f32x4){0.f,0.f,0.f,0.f};
  float m2 = -1e30f, ell = 0.f;                 // per-lane partial ell
  // loop-invariant swizzled LDS read offsets
  const int sw2 = (lr & 7) << 4;
  const int offC0 = lr*128 + ((g*16) ^ sw2);
  const int offC1 = lr*128 + ((g*16 + 64) ^ sw2);

  __syncthreads();                              // prologue tile staged (full drain)

  auto body = [&](int cbuf){
    const char* Kb = (const char*)&Ks[cbuf][0];
    const char* Vb = (const char*)&Vs[cbuf][0];
    // ---- S^T = K @ Q^T : lane holds S[kv = s4*16 + g*4 + r][q = lr] ----
    f32x4 st[4];
    __builtin_amdgcn_s_setprio(1);
    #pragma unroll
    for (int s4=0; s4<4; ++s4){
      bf16x8 k0 = *(const bf16x8*)(Kb + s4*2048 + offC0);
      bf16x8 k1 = *(const bf16x8*)(Kb + s4*2048 + offC1);
      st[s4] = __builtin_amdgcn_mfma_f32_16x16x32_bf16(k0, qf0, Zv,     0,0,0);
      st[s4] = __builtin_amdgcn_mfma_f32_16x16x32_bf16(k1, qf1, st[s4], 0,0,0);
    }
    __builtin_amdgcn_s_setprio(0);

    // ---- V fragments into regs early (LDS pipe works under softmax VALU) ----
    bf16x8 vb0[4], vb1[4];
    #pragma unroll
    for (int d=0; d<4; ++d){
      vb0[d] = *(const bf16x8*)(Vb + d*2048 + offC0);
      vb1[d] = *(const bf16x8*)(Vb + d*2048 + offC1);
    }

    // ---- online softmax, log2 domain, defer-max THR=8 ----
    float t0f = fm3(st[0][0], st[0][1], st[0][2]);
    float t1f = fm3(st[0][3], st[1][0], st[1][1]);
    float t2f = fm3(st[1][2], st[1][3], st[2][0]);
    float t3f = fm3(st[2][1], st[2][2], st[2][3]);
    float t4f = fm3(st[3][0], st[3][1], st[3][2]);
    float tmax = fm3(fm3(t0f, t1f, t2f), fmaxf(t3f, t4f), st[3][3]);
    tmax = fmaxf(tmax, __shfl_xor(tmax, 16));
    tmax = fmaxf(tmax, __shfl_xor(tmax, 32));
    if (__any(tmax > m2 + 8.f)){
      float mn = fmaxf(m2, tmax);
      float sc = ex2(m2 - mn);
      m2 = mn;
      ell *= sc;
      #pragma unroll
      for (int r=0; r<4; ++r){
        float scr = __shfl(sc, g*4 + r);
        #pragma unroll
        for (int d=0; d<4; ++d) Xf[d][r] *= scr;
      }
    }
    #pragma unroll
    for (int s4=0; s4<4; ++s4)
      #pragma unroll
      for (int r=0; r<4; ++r) st[s4][r] = ex2(st[s4][r] - m2);
    float ps0 = (st[0][0]+st[0][1]) + (st[0][2]+st[0][3]);
    float ps1 = (st[1][0]+st[1][1]) + (st[1][2]+st[1][3]);
    float ps2 = (st[2][0]+st[2][1]) + (st[2][2]+st[2][3]);
    float ps3 = (st[3][0]+st[3][1]) + (st[3][2]+st[3][3]);
    ell += (ps0+ps1) + (ps2+ps3);

    // ---- P -> bf16 A-fragments via packed cvt (k-slot map pi unchanged) ----
    u32x4 w0, w1;
    w0[0] = cvtpk(st[0][0], st[0][1]); w0[1] = cvtpk(st[0][2], st[0][3]);
    w0[2] = cvtpk(st[1][0], st[1][1]); w0[3] = cvtpk(st[1][2], st[1][3]);
    w1[0] = cvtpk(st[2][0], st[2][1]); w1[1] = cvtpk(st[2][2], st[2][3]);
    w1[2] = cvtpk(st[3][0], st[3][1]); w1[3] = cvtpk(st[3][2], st[3][3]);
    bf16x8 pa0 = __builtin_bit_cast(bf16x8, w0);
    bf16x8 pa1 = __builtin_bit_cast(bf16x8, w1);

    // ---- X += P @ V  (pure reg MFMA) ----
    __builtin_amdgcn_s_setprio(1);
    #pragma unroll
    for (int d=0; d<4; ++d){
      Xf[d] = __builtin_amdgcn_mfma_f32_16x16x32_bf16(pa0, vb0[d], Xf[d], 0,0,0);
      Xf[d] = __builtin_amdgcn_mfma_f32_16x16x32_bf16(pa1, vb1[d], Xf[d], 0,0,0);
    }
    __builtin_amdgcn_s_setprio(0);
  };

  for (int it = 0; it < SS/64; it += 2){
    { int tt = (it + 1 + rot) & 31; stageK(1, tt); stageV(1, tt); }
    body(0);
    __syncthreads();                            // drains slot-1 loads + WAR fence
    if (it + 2 < SS/64){
      int tt = (it + 2 + rot) & 31;
      stageK(0, tt); stageV(0, tt);
    }
    body(1);
    __syncthreads();
  }

  // ---- finalize: reduce partial ell over lane-groups, divide, store ----
  float elt = ell;
  elt += __shfl_xor(elt, 16);
  elt += __shfl_xor(elt, 32);
  float rinv[4];
  #pragma unroll
  for (int r=0; r<4; ++r) rinv[r] = 1.0f / __shfl(elt, g*4 + r);
  int b = bh >> 4, h = bh & 15;
  #pragma unroll
  for (int d=0; d<4; ++d)
    #pragma unroll
    for (int r=0; r<4; ++r){
      int s = q0 + wid*16 + g*4 + r;
      int col = h*64 + d*16 + lr;
      Xg[((size_t)b*SS + s)*DD + col] = f2bf(Xf[d][r] * rinv[r]);
    }
}

// ---------------- host ----------------
extern "C" void kernel_launch(void* const* d_in, const int* in_sizes, int n_in,
                              void* d_out, int out_size, void* d_ws, size_t ws_size,
                              hipStream_t stream){
  (void)in_sizes; (void)n_in; (void)out_size; (void)ws_size;
  const float* query = (const float*)d_in[0];
  const float* key   = (const float*)d_in[1];
  const float* value = (const float*)d_in[2];
  const float* fc_w  = (const float*)d_in[3];
  const float* Wq    = (const float*)d_in[4];
  const float* bq    = (const float*)d_in[5];
  const float* Wk    = (const float*)d_in[6];
  const float* bk    = (const float*)d_in[7];
  const float* Wv    = (const float*)d_in[8];
  const float* bv    = (const float*)d_in[9];
  const float* Wo    = (const float*)d_in[10];
  const float* bo    = (const float*)d_in[11];

  char* ws = (char*)d_ws;
  const size_t EL = (size_t)BB*SS*DD;          // 8388608 elems
  size_t off = 0;
  auto alloc = [&](size_t bytes){ size_t o = off; off += (bytes + 255) & ~(size_t)255; return o; };
  unsigned short* qb  = (unsigned short*)(ws + alloc(EL*2));
  unsigned short* kb  = (unsigned short*)(ws + alloc(EL*2));
  unsigned short* vb  = (unsigned short*)(ws + alloc(EL*2));
  unsigned short* Wqt = (unsigned short*)(ws + alloc((size_t)DD*DD*2));
  unsigned short* Wkt = (unsigned short*)(ws + alloc((size_t)DD*DD*2));
  unsigned short* Wvt = (unsigned short*)(ws + alloc((size_t)DD*DD*2));
  unsigned short* Wot = (unsigned short*)(ws + alloc((size_t)DD*DD*2));
  unsigned short* Qh  = (unsigned short*)(ws + alloc(EL*2));
  unsigned short* Kh  = (unsigned short*)(ws + alloc(EL*2));
  unsigned short* Vh  = (unsigned short*)(ws + alloc(EL*2));
  // Aliased buffers:
  //   Vth aliases vb (vb dead after V-projection GEMM; transpose runs after it)
  //   Xh  aliases qb (qb dead after Q-projection GEMM; attn runs after it)
  unsigned short* Vth = vb;
  unsigned short* Xh  = qb;

  const float SC2 = 0.18033688011112042f;      // (1/sqrt(64)) * log2(e), folded into Q

  const int nbCvt = (int)(EL / 8 / 256);       // 4096
  cvt_bf16_3<<<dim3(nbCvt, 3), 256, 0, stream>>>(query, key, value, qb, kb, vb);
  prep_weights<<<dim3(1024, 4), 256, 0, stream>>>(fc_w, Wq, Wk, Wv, Wo, Wqt, Wkt, Wvt, Wot);

  gemm_qkv<<<1536, 256, 0, stream>>>(qb, kb, vb, Wqt, Wkt, Wvt, bq, bk, bv, SC2,
                                     Qh, Kh, Vh);

  transpose_v<<<dim3(SS/64, BB*HH), 256, 0, stream>>>(Vh, Vth);
  attn<<<2048, 256, 0, stream>>>(Qh, Kh, Vth, Xh);

  gemm_o<<<512, 256, 0, stream>>>(Xh, Wot, bo, (float*)d_out);
}